// Round 10
// baseline (196.132 us; speedup 1.0000x reference)
//
#include <hip/hip_runtime.h>

#define MDIM 2048   // B
#define KD   2560   // HEAD
#define NHID 2048   // N_HID
#define INF  512
#define NS   40     // K-tiles of 64
#define K8   (KD / 8)   // 320 chunks of 8 ushorts

typedef __attribute__((ext_vector_type(16))) float f32x16;
typedef __attribute__((ext_vector_type(8))) short short8;
typedef __attribute__((ext_vector_type(8))) unsigned short ushort8v;
typedef __attribute__((ext_vector_type(4))) unsigned short ushort4v;

#define AS1 __attribute__((address_space(1)))
#define AS3 __attribute__((address_space(3)))

__device__ __forceinline__ unsigned short f2bf(float f) {
    unsigned u = __float_as_uint(f);
    u += 0x7fffu + ((u >> 16) & 1u);
    return (unsigned short)(u >> 16);
}

// ---- prep: xcF = concat(x,h) -> bf16 in fragment-linear layout [M/32][K8][32][8] ----
// Chunk (rb,k8) holds rows rb*32..+31, k-cols k8*8..+7; gemm A-frag load = one
// coalesced 1024B global_load per wave. LDS transpose keeps both sides coalesced.
__global__ void prep_xcF(const float* __restrict__ x, const float* __restrict__ h,
                         unsigned short* __restrict__ xcF) {
    __shared__ unsigned short st[32][280];   // 280 pad: 16B-aligned rows, ~4-way worst
    const int t = threadIdx.x;               // 256
    const int rb = blockIdx.y, cb = blockIdx.x;
    const int row = t >> 3, c8 = t & 7;
    const int gr = rb * 32 + row;
    #pragma unroll
    for (int it = 0; it < 4; ++it) {
        const int colf = c8 * 8 + it * 64;
        const int col = cb * 256 + colf;
        const float* src = (col < INF) ? (x + (size_t)gr * INF + col)
                                       : (h + (size_t)gr * NHID + (col - INF));
        float4 v0 = *(const float4*)src;
        float4 v1 = *(const float4*)(src + 4);
        ushort8v o;
        o[0] = f2bf(v0.x); o[1] = f2bf(v0.y); o[2] = f2bf(v0.z); o[3] = f2bf(v0.w);
        o[4] = f2bf(v1.x); o[5] = f2bf(v1.y); o[6] = f2bf(v1.z); o[7] = f2bf(v1.w);
        *(ushort8v*)&st[row][colf] = o;
    }
    __syncthreads();
    const int l = t & 63, wv = t >> 6;
    const int orow = l & 31;
    #pragma unroll
    for (int it2 = 0; it2 < 4; ++it2) {
        const int k8l = it2 * 8 + wv * 2 + (l >> 5);
        ushort8v v = *(const ushort8v*)&st[orow][k8l * 8];
        *(ushort8v*)(xcF + ((size_t)(rb * K8 + cb * 32 + k8l) * 32 + orow) * 8) = v;
    }
}

// ---- prep: Wm[k] = W_k * mask -> bf16, 5 planes [5*NHID][KD] (row-major) ----
__global__ void prep_wm(const float* __restrict__ Wg, const float* __restrict__ Wh,
                        const float* __restrict__ Wfg, const float* __restrict__ Wfh,
                        const float* __restrict__ Wp, const float* __restrict__ mask,
                        unsigned short* __restrict__ Wm) {
    int idx = blockIdx.x * 256 + threadIdx.x;
    size_t e = (size_t)idx * 4;
    const size_t PL = (size_t)NHID * KD;
    int col = (int)(e % KD);
    float4 m;
    if (col < INF) m = *(const float4*)(mask + e);
    else           m = make_float4(1.f, 1.f, 1.f, 1.f);
    const float* Ws[5] = {Wg, Wh, Wfg, Wfh, Wp};
    #pragma unroll
    for (int k = 0; k < 5; ++k) {
        float4 w = *(const float4*)(Ws[k] + e);
        ushort4v o;
        o[0] = f2bf(w.x * m.x); o[1] = f2bf(w.y * m.y);
        o[2] = f2bf(w.z * m.z); o[3] = f2bf(w.w * m.w);
        *(ushort4v*)(Wm + k * PL + e) = o;
    }
}

// ---- fused GEMM + epilogue: A from registers (global, frag-linear), B via LDS ----
// 256x64x5 tile, 8 waves 4Mx2N, 32x32x16. B double-buffered 80KB (R7 swizzle,
// 0 conflicts). A double-buffered in regs, 1 tile ahead. Counted-vmcnt ledger
// (per wave 5 B-gloads + 8 A-loads, order pinned): entry vmcnt(13), pre-barrier
// vmcnt(8); B-flight = 2 tiles; NO vmcnt(0) in steady state.
#define MFMA32(d, va, vb) d = __builtin_amdgcn_mfma_f32_32x32x16_bf16(va, vb, d, 0, 0, 0)

__global__ __launch_bounds__(512, 2) void gemm_fused(
    const unsigned short* __restrict__ Af,
    const unsigned short* __restrict__ Bm,
    const float* __restrict__ bg, const float* __restrict__ bh,
    const float* __restrict__ bfg, const float* __restrict__ bfh,
    const float* __restrict__ bp,
    float* __restrict__ out) {
    __shared__ unsigned short lsB[2][320 * 64];   // 80 KB

    const int tid  = threadIdx.x;
    const int lane = tid & 63;
    const int w    = tid >> 6;       // 0..7
    const int wm   = w >> 1;         // 0..3
    const int wn   = w & 1;          // 0..1
    const int l31  = lane & 31;
    const int hi   = lane >> 5;
    const int l7   = lane & 7;
    const int u    = l31 >> 3;
    const int sc   = lane & 7;       // staging slot
    const int su   = lane >> 3;      // staging row-in-group
    const int m0   = blockIdx.y * 256;
    const int n0c  = blockIdx.x * 64;

    // ---- B staging (identical to R7/8: key(row) = (row ^ (row>>3)) & 7) ----
    const int br0 = (w >> 1) * 80 + (w & 1) * 8;   // + 16*j, j=0..4
#define SB(j, t, b) do { \
        const int r0 = br0 + 16 * (j); \
        const int grow = (r0 >> 6) * NHID + n0c + (r0 & 63); \
        const int colv = ((sc ^ su ^ ((r0 >> 3) & 7)) << 3) + (t) * 64; \
        __builtin_amdgcn_global_load_lds( \
            (const AS1 unsigned int*)(Bm + (size_t)(grow + su) * KD + colv), \
            (AS3 unsigned int*)(&lsB[b][r0 * 64]), 16, 0, 0); \
    } while (0)
#define SB5(t, b) do { SB(0,t,b); SB(1,t,b); SB(2,t,b); SB(3,t,b); SB(4,t,b); } while (0)

    // ---- A fragment loads: chunk (rb0+m, kt*8+2s+hi), lane l31 = row ----
    const int rb0 = blockIdx.y * 8 + wm * 2;
    const int lanepartA = hi * 256 + l31 * 8;
#define AFRAG(m, s, KT) (*(const short8*)(Af + (size_t)((rb0 + (m)) * K8 + (KT) * 8 + 2 * (s)) * 256 + lanepartA))
#define ALOAD(SET, KT) do { \
        SET[0] = AFRAG(0,0,KT); SET[1] = AFRAG(0,1,KT); SET[2] = AFRAG(0,2,KT); SET[3] = AFRAG(0,3,KT); \
        SET[4] = AFRAG(1,0,KT); SET[5] = AFRAG(1,1,KT); SET[6] = AFRAG(1,2,KT); SET[7] = AFRAG(1,3,KT); \
    } while (0)

    // B-frag read offsets (R7-verified conflict-free)
    const int brow = wn * 32 + l31;          // + 64*p
    const int keyB = (4 * wn + u) & 7;
    int csB[4];
    #pragma unroll
    for (int s = 0; s < 4; ++s) csB[s] = (((2 * s + hi) ^ l7 ^ keyB) << 3);

    f32x16 acc[2][5] = {};
    short8 a0[8], a1[8];

    // ---- prologue: B0->buf0, A0->a0, B1->buf1, A1->a1; wait B0,A0 ----
    SB5(0, 0);
    __builtin_amdgcn_sched_barrier(0);
    ALOAD(a0, 0);
    __builtin_amdgcn_sched_barrier(0);
    SB5(1, 1);
    __builtin_amdgcn_sched_barrier(0);
    ALOAD(a1, 1);
    __builtin_amdgcn_sched_barrier(0);
    asm volatile("s_waitcnt vmcnt(13)" ::: "memory");
    __builtin_amdgcn_s_barrier();

#define TILE(KT, CUR) do { \
        if ((KT) == NS - 1) asm volatile("s_waitcnt vmcnt(0)" ::: "memory"); \
        else                asm volatile("s_waitcnt vmcnt(13)" ::: "memory"); \
        __builtin_amdgcn_sched_barrier(0); \
        { const int bc_ = (KT) & 1; \
          _Pragma("unroll") \
          for (int s = 0; s < 4; ++s) { \
              short8 bv[5]; \
              _Pragma("unroll") \
              for (int p = 0; p < 5; ++p) \
                  bv[p] = *(const short8*)&lsB[bc_][(brow + 64 * p) * 64 + csB[s]]; \
              __builtin_amdgcn_s_setprio(1); \
              _Pragma("unroll") \
              for (int p = 0; p < 5; ++p) { \
                  MFMA32(acc[0][p], CUR[s], bv[p]); \
                  MFMA32(acc[1][p], CUR[4 + s], bv[p]); \
              } \
              __builtin_amdgcn_s_setprio(0); \
          } } \
        if ((KT) < NS - 1) { \
            asm volatile("s_waitcnt vmcnt(8)" ::: "memory"); \
            __builtin_amdgcn_s_barrier(); \
            __builtin_amdgcn_sched_barrier(0); \
            if ((KT) < NS - 2) { \
                SB5((KT) + 2, (KT) & 1); \
                __builtin_amdgcn_sched_barrier(0); \
                ALOAD(CUR, (KT) + 2); \
                __builtin_amdgcn_sched_barrier(0); \
            } \
        } \
    } while (0)

    for (int kt2 = 0; kt2 < NS; kt2 += 2) {
        TILE(kt2, a0);
        TILE(kt2 + 1, a1);
    }

    // ---- fused epilogue (C/D: col = lane&31, row = (reg&3)+8*(reg>>2)+4*hi) ----
    const int col = n0c + wn * 32 + l31;
    const float bgv = bg[col];
    const float bhv = bh[col];
    const float bfv = bfg[col] + bfh[col];
    const float bpv = bp[col];
    const size_t PL = (size_t)MDIM * NHID;
    #pragma unroll
    for (int m = 0; m < 2; ++m) {
        #pragma unroll
        for (int q = 0; q < 4; ++q) {
            #pragma unroll
            for (int t = 0; t < 4; ++t) {
                const int e = q * 4 + t;
                const int row = m0 + wm * 64 + m * 32 + q * 8 + 4 * hi + t;
                float gx = acc[m][0][e] + bgv;
                float hx = acc[m][1][e] + bhv;
                float sx = acc[m][2][e] + acc[m][3][e] + bfv;
                float tg = __expf(-2.0f * fabsf(gx));
                float g  = __builtin_copysignf((1.0f - tg) / (1.0f + tg), gx);
                float th = __expf(-2.0f * fabsf(hx));
                float hh = __builtin_copysignf((1.0f - th) / (1.0f + th), hx);
                float gate = 1.0f / (1.0f + __expf(-sx));
                float nh = g * (1.0f - gate) + gate * hh;
                float y  = acc[m][4][e] + bpv + nh;
                out[(size_t)row * NHID + col]      = y;
                out[PL + (size_t)row * NHID + col] = nh;
            }
        }
    }
#undef SB
#undef SB5
#undef AFRAG
#undef ALOAD
#undef TILE
}

extern "C" void kernel_launch(void* const* d_in, const int* in_sizes, int n_in,
                              void* d_out, int out_size, void* d_ws, size_t ws_size,
                              hipStream_t stream) {
    const float* x      = (const float*)d_in[0];
    const float* hidden = (const float*)d_in[1];
    const float* mask   = (const float*)d_in[2];
    const float* Wg     = (const float*)d_in[3];
    const float* bg     = (const float*)d_in[4];
    const float* Wh     = (const float*)d_in[5];
    const float* bh     = (const float*)d_in[6];
    const float* Wfg    = (const float*)d_in[7];
    const float* bfg    = (const float*)d_in[8];
    const float* Wfh    = (const float*)d_in[9];
    const float* bfh    = (const float*)d_in[10];
    const float* Wp     = (const float*)d_in[11];
    const float* bp     = (const float*)d_in[12];
    float* out = (float*)d_out;

    const size_t need = (size_t)MDIM * KD * 2 + (size_t)5 * NHID * KD * 2;
    if (ws_size < need) return;

    unsigned short* xcF = (unsigned short*)d_ws;
    unsigned short* Wm  = xcF + (size_t)MDIM * KD;

    dim3 gx_(KD / 256, MDIM / 32);
    prep_xcF<<<gx_, 256, 0, stream>>>(x, hidden, xcF);
    prep_wm<<<NHID * KD / 4 / 256, 256, 0, stream>>>(Wg, Wh, Wfg, Wfh, Wp, mask, Wm);
    dim3 grid(NHID / 64, MDIM / 256);
    gemm_fused<<<grid, 512, 0, stream>>>(xcF, Wm, bg, bh, bfg, bfh, bp, out);
}

// Round 11
// 133.873 us; speedup vs baseline: 1.4651x; 1.4651x over previous
//
#include <hip/hip_runtime.h>

#define MDIM 2048   // B
#define KD   2560   // HEAD
#define NHID 2048   // N_HID
#define INF  512
#define NS   40     // K-tiles of 64

typedef __attribute__((ext_vector_type(16))) float f32x16;
typedef __attribute__((ext_vector_type(8))) short short8;
typedef __attribute__((ext_vector_type(8))) unsigned short ushort8v;
typedef __attribute__((ext_vector_type(4))) unsigned short ushort4v;

#define AS1 __attribute__((address_space(1)))
#define AS3 __attribute__((address_space(3)))

__device__ __forceinline__ unsigned short f2bf(float f) {
    unsigned u = __float_as_uint(f);
    u += 0x7fffu + ((u >> 16) & 1u);
    return (unsigned short)(u >> 16);
}

// ---------------- merged prep: xc (blocks 0..2559) + Wm (blocks 2560..7679) ----------------
#define XCB 2560
__global__ void prep_all(const float* __restrict__ x, const float* __restrict__ h,
                         unsigned short* __restrict__ xc,
                         const float* __restrict__ Wg, const float* __restrict__ Wh,
                         const float* __restrict__ Wfg, const float* __restrict__ Wfh,
                         const float* __restrict__ Wp, const float* __restrict__ mask,
                         unsigned short* __restrict__ Wm) {
    if (blockIdx.x < XCB) {
        int idx = blockIdx.x * 256 + threadIdx.x;
        int e = idx * 8;
        int b = e / KD;
        int c = e - b * KD;
        const float* src = (c < INF) ? (x + (size_t)b * INF + c)
                                     : (h + (size_t)b * NHID + (c - INF));
        float4 v0 = *(const float4*)src;
        float4 v1 = *(const float4*)(src + 4);
        ushort8v o;
        o[0] = f2bf(v0.x); o[1] = f2bf(v0.y); o[2] = f2bf(v0.z); o[3] = f2bf(v0.w);
        o[4] = f2bf(v1.x); o[5] = f2bf(v1.y); o[6] = f2bf(v1.z); o[7] = f2bf(v1.w);
        *(ushort8v*)(xc + e) = o;
    } else {
        int idx = (blockIdx.x - XCB) * 256 + threadIdx.x;
        size_t e = (size_t)idx * 4;
        const size_t PL = (size_t)NHID * KD;
        int col = (int)(e % KD);
        float4 m;
        if (col < INF) m = *(const float4*)(mask + e);
        else           m = make_float4(1.f, 1.f, 1.f, 1.f);
        const float* Ws[5] = {Wg, Wh, Wfg, Wfh, Wp};
        #pragma unroll
        for (int k = 0; k < 5; ++k) {
            float4 w = *(const float4*)(Ws[k] + e);
            ushort4v o;
            o[0] = f2bf(w.x * m.x); o[1] = f2bf(w.y * m.y);
            o[2] = f2bf(w.z * m.z); o[3] = f2bf(w.w * m.w);
            *(ushort4v*)(Wm + k * PL + e) = o;
        }
    }
}

// ---------------- fused GEMM + epilogue (R8 structure, addressing-hoisted) ----------------
// 256x64x5 tile, 8 waves 4Mx2N, 32x32x16, LDS dbuf 144KB, fused epilogue.
// Changes vs R8 (targeting the measured ~1600 cyc/K-tile addressing VALU):
//  - staging: per-lane 32-bit offsets hoisted (4 A + 5 B), uniform bases
//    advanced 128 B/tile (scalar) -> saddr-form, ~0 VALU per tile.
//  - kt loop unrolled x2 with literal buffer index -> ds_read addrs fold to
//    loop-invariant VGPR + immediate.
// Swizzle (R7-verified, 0 conflicts): LDS[r][s] = G[r][s ^ ((r^(r>>3))&7)].
#define MFMA32(d, va, vb) d = __builtin_amdgcn_mfma_f32_32x32x16_bf16(va, vb, d, 0, 0, 0)

__global__ __launch_bounds__(512, 2) void gemm_fused(
    const unsigned short* __restrict__ A,
    const unsigned short* __restrict__ Bm,
    const float* __restrict__ bg, const float* __restrict__ bh,
    const float* __restrict__ bfg, const float* __restrict__ bfh,
    const float* __restrict__ bp,
    float* __restrict__ out) {
    __shared__ unsigned short lsA[2][256 * 64];   // 64 KB
    __shared__ unsigned short lsB[2][320 * 64];   // 80 KB

    const int tid  = threadIdx.x;
    const int lane = tid & 63;
    const int w    = tid >> 6;       // 0..7
    const int wm   = w >> 1;         // 0..3
    const int wn   = w & 1;          // 0..1
    const int l31  = lane & 31;
    const int hi   = lane >> 5;
    const int l7   = lane & 7;
    const int u    = l31 >> 3;
    const int sc   = lane & 7;       // staging slot
    const int su   = lane >> 3;      // staging row-in-group (0..7)
    const int m0   = blockIdx.y * 256;
    const int n0c  = blockIdx.x * 64;

    const int ar0 = (w >> 2) * 128 + (w & 3) * 8;   // + 32*j
    const int br0 = (w >> 1) * 80 + (w & 1) * 8;    // + 16*j

    // ---- hoisted per-lane staging source offsets (bytes) ----
    unsigned aOff[4], bOff[5];
    #pragma unroll
    for (int j = 0; j < 4; ++j) {
        const int r0 = ar0 + 32 * j;
        const int colv = ((sc ^ su ^ ((r0 >> 3) & 7)) << 3);
        aOff[j] = (unsigned)(((r0 + su) * KD + colv) * 2);
    }
    #pragma unroll
    for (int j = 0; j < 5; ++j) {
        const int r0 = br0 + 16 * j;
        const int grow = (r0 >> 6) * NHID + n0c + (r0 & 63);
        const int colv = ((sc ^ su ^ ((r0 >> 3) & 7)) << 3);
        bOff[j] = (unsigned)(((grow + su) * KD + colv) * 2);
    }
    const char* aBase = (const char*)A + (size_t)m0 * KD * 2;   // advances 128 B/tile
    const char* bBase = (const char*)Bm;                         // advances 128 B/tile

#define STG(buf) do { \
        _Pragma("unroll") \
        for (int j = 0; j < 4; ++j) \
            __builtin_amdgcn_global_load_lds( \
                (const AS1 unsigned int*)(aBase + aOff[j]), \
                (AS3 unsigned int*)(&lsA[buf][(ar0 + 32 * j) * 64]), 16, 0, 0); \
        _Pragma("unroll") \
        for (int j = 0; j < 5; ++j) \
            __builtin_amdgcn_global_load_lds( \
                (const AS1 unsigned int*)(bBase + bOff[j]), \
                (AS3 unsigned int*)(&lsB[buf][(br0 + 16 * j) * 64]), 16, 0, 0); \
        aBase += 128; bBase += 128; \
    } while (0)

    // ---- hoisted ds_read byte offsets ----
    const int arow = wm * 64 + l31;    // + 32*m
    const int brow = wn * 32 + l31;    // + 64*p
    const int keyB = (4 * wn + u) & 7;
    unsigned aRd[2][4], bRd[4];
    #pragma unroll
    for (int s = 0; s < 4; ++s) {
        #pragma unroll
        for (int m = 0; m < 2; ++m)
            aRd[m][s] = (unsigned)(((arow + 32 * m) * 64
                       + (((2 * s + hi) ^ l7 ^ ((4 * m + u) & 7)) << 3)) * 2);
        bRd[s] = (unsigned)((brow * 64 + (((2 * s + hi) ^ l7 ^ keyB) << 3)) * 2);
    }

    f32x16 acc[2][5] = {};

#define COMPUTE(bcl) do { \
        const char* baseA_ = (const char*)&lsA[bcl][0]; \
        const char* baseB_ = (const char*)&lsB[bcl][0]; \
        _Pragma("unroll") \
        for (int s = 0; s < 4; ++s) { \
            short8 av[2], bv[5]; \
            _Pragma("unroll") \
            for (int m = 0; m < 2; ++m) \
                av[m] = *(const short8*)(baseA_ + aRd[m][s]); \
            _Pragma("unroll") \
            for (int p = 0; p < 5; ++p) \
                bv[p] = *(const short8*)(baseB_ + bRd[s] + p * 8192); \
            __builtin_amdgcn_s_setprio(1); \
            _Pragma("unroll") \
            for (int m = 0; m < 2; ++m) \
                _Pragma("unroll") \
                for (int p = 0; p < 5; ++p) \
                    MFMA32(acc[m][p], av[m], bv[p]); \
            __builtin_amdgcn_s_setprio(0); \
        } \
    } while (0)

#define ENDBAR() do { \
        asm volatile("s_waitcnt vmcnt(0)" ::: "memory"); \
        __builtin_amdgcn_s_barrier(); \
    } while (0)

    // prologue: stage tile 0 -> buf 0
    STG(0);
    ENDBAR();

    for (int kt = 0; kt < NS; kt += 2) {
        // even tile: buf0; stage kt+1 -> buf1 (kt <= 38 so kt+1 < NS always)
        STG(1);
        COMPUTE(0);
        ENDBAR();
        // odd tile: buf1; stage kt+2 -> buf0
        if (kt + 2 < NS) STG(0);
        COMPUTE(1);
        ENDBAR();
    }

    // ---- fused epilogue (C/D: col = lane&31, row = (reg&3)+8*(reg>>2)+4*hi) ----
    const int col = n0c + wn * 32 + l31;
    const float bgv = bg[col];
    const float bhv = bh[col];
    const float bfv = bfg[col] + bfh[col];
    const float bpv = bp[col];
    const size_t PL = (size_t)MDIM * NHID;
    #pragma unroll
    for (int m = 0; m < 2; ++m) {
        #pragma unroll
        for (int q = 0; q < 4; ++q) {
            #pragma unroll
            for (int t = 0; t < 4; ++t) {
                const int e = q * 4 + t;
                const int row = m0 + wm * 64 + m * 32 + q * 8 + 4 * hi + t;
                float gx = acc[m][0][e] + bgv;
                float hx = acc[m][1][e] + bhv;
                float sx = acc[m][2][e] + acc[m][3][e] + bfv;
                float tg = __expf(-2.0f * fabsf(gx));
                float g  = __builtin_copysignf((1.0f - tg) / (1.0f + tg), gx);
                float th = __expf(-2.0f * fabsf(hx));
                float hh = __builtin_copysignf((1.0f - th) / (1.0f + th), hx);
                float gate = 1.0f / (1.0f + __expf(-sx));
                float nh = g * (1.0f - gate) + gate * hh;
                float y  = acc[m][4][e] + bpv + nh;
                out[(size_t)row * NHID + col]      = y;
                out[PL + (size_t)row * NHID + col] = nh;
            }
        }
    }
#undef STG
#undef COMPUTE
#undef ENDBAR
}

extern "C" void kernel_launch(void* const* d_in, const int* in_sizes, int n_in,
                              void* d_out, int out_size, void* d_ws, size_t ws_size,
                              hipStream_t stream) {
    const float* x      = (const float*)d_in[0];
    const float* hidden = (const float*)d_in[1];
    const float* mask   = (const float*)d_in[2];
    const float* Wg     = (const float*)d_in[3];
    const float* bg     = (const float*)d_in[4];
    const float* Wh     = (const float*)d_in[5];
    const float* bh     = (const float*)d_in[6];
    const float* Wfg    = (const float*)d_in[7];
    const float* bfg    = (const float*)d_in[8];
    const float* Wfh    = (const float*)d_in[9];
    const float* bfh    = (const float*)d_in[10];
    const float* Wp     = (const float*)d_in[11];
    const float* bp     = (const float*)d_in[12];
    float* out = (float*)d_out;

    const size_t need = (size_t)MDIM * KD * 2 + (size_t)5 * NHID * KD * 2;
    if (ws_size < need) return;

    unsigned short* xc = (unsigned short*)d_ws;
    unsigned short* Wm = xc + (size_t)MDIM * KD;

    prep_all<<<XCB + NHID * KD / 4 / 256, 256, 0, stream>>>(
        x, hidden, xc, Wg, Wh, Wfg, Wfh, Wp, mask, Wm);
    dim3 grid(NHID / 64, MDIM / 256);
    gemm_fused<<<grid, 512, 0, stream>>>(xc, Wm, bg, bh, bfg, bfh, bp, out);
}